// Round 11
// baseline (682.122 us; speedup 1.0000x reference)
//
#include <hip/hip_runtime.h>
#include <hip/hip_bf16.h>
#include <stdint.h>

#define DEVI __device__ __forceinline__

typedef __bf16 bf16x8_t __attribute__((ext_vector_type(8)));
typedef float f32x4_t __attribute__((ext_vector_type(4)));
typedef unsigned short u16;

static constexpr int NBATCH = 16;
static constexpr int NV = 1024;
static constexpr int NE = 2048;
static constexpr int FV = 128;
static constexpr int FE = 64;
static constexpr int HID = 128;
static constexpr int NCLS = 16;

DEVI u16 f2bf(float f) { __hip_bfloat16 h = __float2bfloat16(f); return *reinterpret_cast<u16*>(&h); }
DEVI float bf2f(u16 u) { union { unsigned int i; float f; } x; x.i = ((unsigned int)u) << 16; return x.f; }

DEVI void gload_lds16(const void* g, void* l) {
  __builtin_amdgcn_global_load_lds(
      (const __attribute__((address_space(1))) unsigned int*)g,
      (__attribute__((address_space(3))) unsigned int*)l, 16, 0, 0);
}

// out[j] = bf16( bf16(a[j]) * bf16(d[j]) )  -- 8 bf16 lanes packed in uint4
DEVI uint4 scale_pack(uint4 a, uint4 d) {
  unsigned int* ap = (unsigned int*)&a;
  unsigned int* dp = (unsigned int*)&d;
  uint4 o;
  unsigned int* op = (unsigned int*)&o;
  #pragma unroll
  for (int w = 0; w < 4; ++w) {
    float lo = bf2f(ap[w] & 0xffff) * bf2f(dp[w] & 0xffff);
    float hi = bf2f(ap[w] >> 16) * bf2f(dp[w] >> 16);
    op[w] = (unsigned int)f2bf(lo) | ((unsigned int)f2bf(hi) << 16);
  }
  return o;
}

// ---- K0: T (f32) -> T_bf (row-major bf16) + Tt_bf (transposed bf16) ----
__global__ void k_transpose(const float* __restrict__ T, u16* __restrict__ Tbf,
                            u16* __restrict__ Ttbf) {
  __shared__ u16 s[32][33];
  const int b = blockIdx.z;
  const int e0 = blockIdx.x * 32, v0 = blockIdx.y * 32;
  const float* Tb = T + (size_t)b * NV * NE;
  u16* T1 = Tbf + (size_t)b * NV * NE;
  u16* T2 = Ttbf + (size_t)b * NE * NV;
  const int tx = threadIdx.x & 31, ty = threadIdx.x >> 5;
  #pragma unroll
  for (int i = 0; i < 4; ++i) {
    int v = v0 + ty + i * 8;
    u16 u = f2bf(Tb[(size_t)v * NE + e0 + tx]);
    T1[(size_t)v * NE + e0 + tx] = u;
    s[ty + i * 8][tx] = u;
  }
  __syncthreads();
  #pragma unroll
  for (int i = 0; i < 4; ++i) {
    int e = e0 + ty + i * 8;
    T2[(size_t)e * NV + v0 + tx] = s[tx][ty + i * 8];
  }
}

// ---- K1: d[b,r] = bf16( sum_c In[b,r,c] * p[c] ) ---- (one wave per row)
__global__ void k_rowdot(const float* __restrict__ In, const float* __restrict__ p,
                         u16* __restrict__ d, int R, int C) {
  const int b = blockIdx.y;
  const int w = threadIdx.x >> 6, l = threadIdx.x & 63;
  const int r = blockIdx.x * 4 + w;
  const float* row = In + ((size_t)b * R + r) * C;
  float s = 0.f;
  for (int c = l; c < C; c += 64) s += row[c] * p[c];
  #pragma unroll
  for (int o = 32; o; o >>= 1) s += __shfl_xor(s, o);
  if (l == 0) d[(size_t)b * R + r] = f2bf(s);
}

// ---- K3: 256x256-tile GEMM  P[bi] = (diag?1:(T diag(d) T^T)) * adj[bg] ----
// A-operand = TA rows [tm,tm+256) with diag(d) folded during REG-STAGING
// (T14: load->scale->ds_write in MFMA gaps); B-operand = TB rows [tn,tn+256)
// via global_load_lds. Round-6 schedule otherwise: stage-early, 1 barrier per
// K-tile, T2 XOR swizzle via inverse-swizzled source, XCD swizzle, setprio.
// Epilogue: diag=1, *adj, bf16 P store, per-block colmax pmax (no atomics).
__global__ __launch_bounds__(512, 2) void k_gemm256(
    const u16* __restrict__ TA, const u16* __restrict__ dvec,
    const u16* __restrict__ TB, size_t sT, int ld,
    int M, int K,
    const float* __restrict__ adj, u16* __restrict__ Pout,
    float* __restrict__ pmax, int b0) {
  extern __shared__ __align__(16) char smem[];
  const int gx = gridDim.x, gy = gridDim.y;
  const int total = gx * gy * gridDim.z;
  int orig = blockIdx.x + gx * (blockIdx.y + gy * blockIdx.z);
  const int cpx = total >> 3;
  int swz = (orig & 7) * cpx + (orig >> 3);
  const int bx = swz % gx;
  const int by = (swz / gx) % gy;
  const int bi = swz / (gx * gy);
  const int bg = b0 + bi;

  const u16* Ab = TA + (size_t)bg * sT;
  const u16* Bb = TB + (size_t)bg * sT;
  const u16* dK = dvec + (size_t)bg * K;
  const int tm = by * 256, tn = bx * 256;
  const int tid = threadIdx.x, wid = tid >> 6, l = tid & 63;
  const int wr = wid >> 2, wc = wid & 3;

  const int srow = tid >> 3;
  const int scol = (((tid & 7) ^ (srow & 7)) << 3);  // elems, inverse-swizzled k

  const int Lx = (l & 7) << 4;
  const int colb0 = (((l >> 4) << 4)) ^ Lx;
  const int colb1 = (64 + ((l >> 4) << 4)) ^ Lx;
  const int arowb = (wr * 128 + (l & 15)) * 128;
  const int browb = (wc * 64 + (l & 15)) * 128;

  auto stageB = [&](char* bb, int k0) {
    #pragma unroll
    for (int i = 0; i < 4; ++i)
      gload_lds16(Bb + (size_t)(tn + i * 64 + srow) * ld + (k0 + scol),
                  bb + i * 8192 + tid * 16);
  };
  auto loadA = [&](int part, int k0) -> uint4 {
    return *(const uint4*)(Ab + (size_t)(tm + part * 64 + srow) * ld + (k0 + scol));
  };

  f32x4_t acc[8][4];
  const f32x4_t zv = {0.f, 0.f, 0.f, 0.f};
  #pragma unroll
  for (int m = 0; m < 8; ++m)
    #pragma unroll
    for (int n = 0; n < 4; ++n) acc[m][n] = zv;

  const int NT = K >> 6;
  // prologue: tile 0 -> buffer 0
  {
    char* ab = smem;
    stageB(ab + 32768, 0);
    uint4 dr = *(const uint4*)(dK + scol);
    #pragma unroll
    for (int i = 0; i < 4; ++i) {
      uint4 a = loadA(i, 0);
      *(uint4*)(ab + i * 8192 + tid * 16) = scale_pack(a, dr);
    }
  }
  __syncthreads();

  for (int kt = 0; kt < NT; ++kt) {
    const int buf = kt & 1;
    char* abase = smem + (buf << 16);
    char* bbase = abase + 32768;
    char* nab = smem + ((buf ^ 1) << 16);
    const int nk0 = (kt + 1) << 6;
    const bool pre = (kt + 1 < NT);

    uint4 a01[2], dr;
    if (pre) {
      stageB(nab + 32768, nk0);
      dr = *(const uint4*)(dK + nk0 + scol);
      a01[0] = loadA(0, nk0);
      a01[1] = loadA(1, nk0);
    }

    bf16x8_t af[4][2], bfr[4][2];
    #pragma unroll
    for (int m = 0; m < 4; ++m) {
      af[m][0] = *(const bf16x8_t*)(abase + arowb + m * 2048 + colb0);
      af[m][1] = *(const bf16x8_t*)(abase + arowb + m * 2048 + colb1);
    }
    #pragma unroll
    for (int n = 0; n < 2; ++n) {
      bfr[n][0] = *(const bf16x8_t*)(bbase + browb + n * 2048 + colb0);
      bfr[n][1] = *(const bf16x8_t*)(bbase + browb + n * 2048 + colb1);
    }
    __builtin_amdgcn_s_setprio(1);
    #pragma unroll
    for (int m = 0; m < 4; ++m)
      #pragma unroll
      for (int n = 0; n < 2; ++n)
        #pragma unroll
        for (int kk = 0; kk < 2; ++kk)
          acc[m][n] = __builtin_amdgcn_mfma_f32_16x16x32_bf16(af[m][kk], bfr[n][kk], acc[m][n], 0, 0, 0);
    __builtin_amdgcn_s_setprio(0);
    #pragma unroll
    for (int n = 2; n < 4; ++n) {
      bfr[n][0] = *(const bf16x8_t*)(bbase + browb + n * 2048 + colb0);
      bfr[n][1] = *(const bf16x8_t*)(bbase + browb + n * 2048 + colb1);
    }
    __builtin_amdgcn_s_setprio(1);
    #pragma unroll
    for (int m = 0; m < 4; ++m)
      #pragma unroll
      for (int n = 2; n < 4; ++n)
        #pragma unroll
        for (int kk = 0; kk < 2; ++kk)
          acc[m][n] = __builtin_amdgcn_mfma_f32_16x16x32_bf16(af[m][kk], bfr[n][kk], acc[m][n], 0, 0, 0);
    __builtin_amdgcn_s_setprio(0);

    uint4 a23[2];
    if (pre) {
      // scale+publish A parts 0,1 (loads issued ~2 MFMA clusters ago)
      *(uint4*)(nab + 0 * 8192 + tid * 16) = scale_pack(a01[0], dr);
      *(uint4*)(nab + 1 * 8192 + tid * 16) = scale_pack(a01[1], dr);
      a23[0] = loadA(2, nk0);
      a23[1] = loadA(3, nk0);
    }

    #pragma unroll
    for (int m = 0; m < 4; ++m) {
      af[m][0] = *(const bf16x8_t*)(abase + arowb + (m + 4) * 2048 + colb0);
      af[m][1] = *(const bf16x8_t*)(abase + arowb + (m + 4) * 2048 + colb1);
    }
    __builtin_amdgcn_s_setprio(1);
    #pragma unroll
    for (int m = 0; m < 4; ++m)
      #pragma unroll
      for (int n = 2; n < 4; ++n)
        #pragma unroll
        for (int kk = 0; kk < 2; ++kk)
          acc[m + 4][n] = __builtin_amdgcn_mfma_f32_16x16x32_bf16(af[m][kk], bfr[n][kk], acc[m + 4][n], 0, 0, 0);
    __builtin_amdgcn_s_setprio(0);
    __builtin_amdgcn_s_setprio(1);
    #pragma unroll
    for (int m = 0; m < 4; ++m)
      #pragma unroll
      for (int n = 0; n < 2; ++n)
        #pragma unroll
        for (int kk = 0; kk < 2; ++kk)
          acc[m + 4][n] = __builtin_amdgcn_mfma_f32_16x16x32_bf16(af[m][kk], bfr[n][kk], acc[m + 4][n], 0, 0, 0);
    __builtin_amdgcn_s_setprio(0);

    if (pre) {
      *(uint4*)(nab + 2 * 8192 + tid * 16) = scale_pack(a23[0], dr);
      *(uint4*)(nab + 3 * 8192 + tid * 16) = scale_pack(a23[1], dr);
    }
    __syncthreads();  // drains B gload_lds + A ds_writes; next tile resident
  }

  // ---- epilogue: diag=1, * adj, bf16 store, per-block column max ----
  const float* adjb = adj + (size_t)bg * M * M;
  u16* Pb = Pout + (size_t)bi * (size_t)M * M;
  float vmax[4] = {0.f, 0.f, 0.f, 0.f};
  #pragma unroll
  for (int m = 0; m < 8; ++m)
    #pragma unroll
    for (int n = 0; n < 4; ++n)
      #pragma unroll
      for (int q = 0; q < 4; ++q) {
        int row = tm + wr * 128 + m * 16 + (l >> 4) * 4 + q;
        int col = tn + wc * 64 + n * 16 + (l & 15);
        float v = acc[m][n][q];
        if (row == col) v = 1.0f;
        v *= adjb[(size_t)row * M + col];
        vmax[n] = fmaxf(vmax[n], v);
        Pb[(size_t)row * M + col] = f2bf(v);
      }
  #pragma unroll
  for (int n = 0; n < 4; ++n) {
    vmax[n] = fmaxf(vmax[n], __shfl_xor(vmax[n], 16));
    vmax[n] = fmaxf(vmax[n], __shfl_xor(vmax[n], 32));
  }
  float* red = (float*)smem;
  if (l < 16) {
    #pragma unroll
    for (int n = 0; n < 4; ++n)
      red[((wr * 4 + wc) * 4 + n) * 16 + l] = vmax[n];
  }
  __syncthreads();
  if (wr == 0 && l < 16) {
    #pragma unroll
    for (int n = 0; n < 4; ++n) {
      float a = red[((0 * 4 + wc) * 4 + n) * 16 + l];
      float b = red[((1 * 4 + wc) * 4 + n) * 16 + l];
      pmax[((size_t)bi * gy + by) * M + tn + wc * 64 + n * 16 + l] = fmaxf(a, b);
    }
  }
}

// ---- K7: skinny 128x64-tile GEMM for P@Yc (col-sliced grid.x) ----
template <int EPI>
__global__ __launch_bounds__(256) void k_gemmPY(
    const u16* __restrict__ A, size_t sA, int ldA,
    const u16* __restrict__ Bm, size_t sB,
    int M, int K, int Ncols,
    const float* __restrict__ bias, float* __restrict__ Fout, int b0) {
  __shared__ __align__(16) u16 As[2][128 * 32];
  __shared__ __align__(16) u16 Bs[2][64 * 32];
  const int bi = blockIdx.z, bg = b0 + bi;
  const u16* Ab = A + (size_t)bi * sA;
  const u16* Bb = Bm + (size_t)bg * sB;
  const int tm = blockIdx.y * 128;
  const int cbase = blockIdx.x * 64;
  const int tid = threadIdx.x, w = tid >> 6, l = tid & 63;
  const int wm = (w >> 1) * 64, wn = (w & 1) * 32;
  const int lr = l & 15, kg = (l >> 4) * 8;
  const int chunk = l & 3;
  int arow[2];
  #pragma unroll
  for (int i = 0; i < 2; ++i) arow[i] = tm + (i * 4 + w) * 16 + (l >> 2);
  int brow = cbase + w * 16 + (l >> 2);
  if (brow >= Ncols) brow = Ncols - 1;

  f32x4_t acc[4][2];
  const f32x4_t zv = {0.f, 0.f, 0.f, 0.f};
  #pragma unroll
  for (int m = 0; m < 4; ++m)
    #pragma unroll
    for (int n = 0; n < 2; ++n) acc[m][n] = zv;

  auto stage = [&](int buf, int k0) {
    #pragma unroll
    for (int i = 0; i < 2; ++i)
      gload_lds16(Ab + (size_t)arow[i] * ldA + k0 + chunk * 8,
                  (char*)As[buf] + (i * 4 + w) * 1024);
    gload_lds16(Bb + (size_t)brow * ldA + k0 + chunk * 8,
                (char*)Bs[buf] + tid * 16);
  };

  const int nsteps = K >> 5;
  stage(0, 0);
  __syncthreads();
  for (int s = 0; s < nsteps; ++s) {
    const int cur = s & 1;
    if (s + 1 < nsteps) stage(cur ^ 1, (s + 1) << 5);
    bf16x8_t af[4], bfr[2];
    #pragma unroll
    for (int m = 0; m < 4; ++m) af[m] = *(const bf16x8_t*)&As[cur][(wm + m * 16 + lr) * 32 + kg];
    #pragma unroll
    for (int n = 0; n < 2; ++n) bfr[n] = *(const bf16x8_t*)&Bs[cur][(wn + n * 16 + lr) * 32 + kg];
    #pragma unroll
    for (int m = 0; m < 4; ++m)
      #pragma unroll
      for (int n = 0; n < 2; ++n)
        acc[m][n] = __builtin_amdgcn_mfma_f32_16x16x32_bf16(af[m], bfr[n], acc[m][n], 0, 0, 0);
    __syncthreads();
  }

  float* Ob = Fout + (size_t)bg * M * Ncols;
  #pragma unroll
  for (int m = 0; m < 4; ++m)
    #pragma unroll
    for (int n = 0; n < 2; ++n)
      #pragma unroll
      for (int q = 0; q < 4; ++q) {
        int row = tm + wm + m * 16 + (l >> 4) * 4 + q;
        int col = cbase + wn + n * 16 + lr;
        if (col < Ncols) {
          float v = acc[m][n][q] + bias[col];
          if (EPI == 1) v = fmaxf(v, 0.f);
          Ob[(size_t)row * Ncols + col] = v;
        }
      }
}

// ---- K5: YT[bg, c, j] = bf16( (X@W)[j,c] / colmax_j ), colmax fused from pmax ----
template <bool RELU_IN>
__global__ __launch_bounds__(256) void k_smallgemm(
    const float* __restrict__ X, size_t sX, int Kd,
    const float* __restrict__ W, int Cc,
    const float* __restrict__ pmax, int G, u16* __restrict__ YT, size_t sY,
    int Nj, int b0) {
  __shared__ float Xs[64][129];
  __shared__ float Ws[128][33];
  const int bi = blockIdx.y, bg = b0 + bi;
  const float* Xb = X + (size_t)bg * sX;
  const int j0 = blockIdx.x * 64;
  const int tid = threadIdx.x;
  for (int idx = tid; idx < 64 * (Kd / 4); idx += 256) {
    int r = idx / (Kd / 4), q = idx % (Kd / 4);
    float4 v = *(const float4*)(Xb + (size_t)(j0 + r) * Kd + q * 4);
    if (RELU_IN) {
      v.x = fmaxf(v.x, 0.f); v.y = fmaxf(v.y, 0.f);
      v.z = fmaxf(v.z, 0.f); v.w = fmaxf(v.w, 0.f);
    }
    Xs[r][q * 4 + 0] = v.x; Xs[r][q * 4 + 1] = v.y;
    Xs[r][q * 4 + 2] = v.z; Xs[r][q * 4 + 3] = v.w;
  }
  const int r = tid & 63, cg = tid >> 6;
  float mx = 0.f;
  {
    const float* pb = pmax + (size_t)bi * G * Nj + (j0 + r);
    for (int g = 0; g < G; ++g) mx = fmaxf(mx, pb[(size_t)g * Nj]);
  }
  const float rinv = 1.0f / mx;
  for (int c0 = 0; c0 < Cc; c0 += 32) {
    __syncthreads();
    for (int idx = tid; idx < Kd * 32; idx += 256) {
      int k = idx >> 5, c = c0 + (idx & 31);
      Ws[k][idx & 31] = (c < Cc) ? W[(size_t)k * Cc + c] : 0.f;
    }
    __syncthreads();
    float acc[8] = {0.f, 0.f, 0.f, 0.f, 0.f, 0.f, 0.f, 0.f};
    for (int k = 0; k < Kd; ++k) {
      float xv = Xs[r][k];
      #pragma unroll
      for (int cc = 0; cc < 8; ++cc) acc[cc] += xv * Ws[k][cg * 8 + cc];
    }
    #pragma unroll
    for (int cc = 0; cc < 8; ++cc) {
      int c = c0 + cg * 8 + cc;
      if (c < Cc) YT[(size_t)bg * sY + (size_t)c * Nj + j0 + r] = f2bf(acc[cc] * rinv);
    }
  }
}

extern "C" void kernel_launch(void* const* d_in, const int* in_sizes, int n_in,
                              void* d_out, int out_size, void* d_ws, size_t ws_size,
                              hipStream_t stream) {
  const float* X    = (const float*)d_in[0];
  const float* Z    = (const float*)d_in[1];
  const float* adje = (const float*)d_in[2];
  const float* adjv = (const float*)d_in[3];
  const float* T    = (const float*)d_in[4];
  const float* W1   = (const float*)d_in[5];
  const float* b1   = (const float*)d_in[6];
  const float* p1   = (const float*)d_in[7];
  const float* W2   = (const float*)d_in[8];
  const float* b2   = (const float*)d_in[9];
  const float* p2   = (const float*)d_in[10];
  const float* W3   = (const float*)d_in[11];
  const float* b3   = (const float*)d_in[12];
  const float* p3   = (const float*)d_in[13];
  float* out = (float*)d_out;
  (void)in_sizes; (void)n_in; (void)out_size;

  hipFuncSetAttribute(reinterpret_cast<const void*>(k_gemm256),
                      hipFuncAttributeMaxDynamicSharedMemorySize, 131072);

  char* ws = (char*)d_ws;
  size_t off = 0;
  auto alloc = [&](size_t n) -> char* {
    char* p = ws + off; off = (off + n + 255) & ~(size_t)255; return p;
  };
  u16* Tbf    = (u16*)alloc((size_t)NBATCH * NV * NE * 2);
  u16* Ttbf   = (u16*)alloc((size_t)NBATCH * NE * NV * 2);
  u16* dbuf   = (u16*)alloc((size_t)NBATCH * NE * 2);
  float* pmax = (float*)alloc((size_t)NBATCH * 16 * NE * 4);
  u16* YT     = (u16*)alloc((size_t)NBATCH * NE * 64 * 2);
  float* x1   = (float*)alloc((size_t)NBATCH * NV * HID * 4);
  float* z2   = (float*)alloc((size_t)NBATCH * NE * FE * 4);
  const size_t needP = (size_t)NBATCH * NE * NE * 2;
  const bool full = (ws_size >= off + needP + 1024);
  const int nb = full ? NBATCH : 1;
  u16* P = (u16*)alloc(full ? needP : (size_t)NE * NE * 2);

  const dim3 blk(256, 1, 1);
  const dim3 blk512(512, 1, 1);

  k_rowdot<<<dim3(NE / 4, NBATCH), blk, 0, stream>>>(Z, p1, dbuf, NE, FE);
  k_transpose<<<dim3(NE / 32, NV / 32, NBATCH), blk, 0, stream>>>(T, Tbf, Ttbf);

  // ---------------- Layer 1 (node: Fv -> H) ----------------
  for (int b0 = 0; b0 < NBATCH; b0 += nb) {
    k_gemm256<<<dim3(NV / 256, NV / 256, nb), blk512, 131072, stream>>>(
        Tbf, dbuf, Tbf, (size_t)NV * NE, NE, NV, NE, adjv, P, pmax, b0);
    k_smallgemm<false><<<dim3(NV / 64, nb), blk, 0, stream>>>(
        X, (size_t)NV * FV, FV, W1, HID, pmax, NV / 256, YT, (size_t)NV * HID, NV, b0);
    k_gemmPY<1><<<dim3(2, NV / 128, nb), blk, 0, stream>>>(
        P, (size_t)NV * NV, NV, YT, (size_t)NV * HID,
        NV, NV, HID, b1, x1, b0);
  }
  // ---------------- Layer 2 (edge: Fe -> Fe) ----------------
  k_rowdot<<<dim3(NV / 4, NBATCH), blk, 0, stream>>>(x1, p2, dbuf, NV, HID);
  for (int b0 = 0; b0 < NBATCH; b0 += nb) {
    k_gemm256<<<dim3(NE / 256, NE / 256, nb), blk512, 131072, stream>>>(
        Ttbf, dbuf, Ttbf, (size_t)NE * NV, NV, NE, NV, adje, P, pmax, b0);
    k_smallgemm<true><<<dim3(NE / 64, nb), blk, 0, stream>>>(
        Z, (size_t)NE * FE, FE, W2, FE, pmax, NE / 256, YT, (size_t)NE * FE, NE, b0);
    k_gemmPY<1><<<dim3(1, NE / 128, nb), blk, 0, stream>>>(
        P, (size_t)NE * NE, NE, YT, (size_t)NE * FE,
        NE, NE, FE, b2, z2, b0);
  }
  // ---------------- Layer 3 (node: H -> C) ----------------
  k_rowdot<<<dim3(NE / 4, NBATCH), blk, 0, stream>>>(z2, p3, dbuf, NE, FE);
  for (int b0 = 0; b0 < NBATCH; b0 += nb) {
    k_gemm256<<<dim3(NV / 256, NV / 256, nb), blk512, 131072, stream>>>(
        Tbf, dbuf, Tbf, (size_t)NV * NE, NE, NV, NE, adjv, P, pmax, b0);
    k_smallgemm<false><<<dim3(NV / 64, nb), blk, 0, stream>>>(
        x1, (size_t)NV * HID, HID, W3, NCLS, pmax, NV / 256, YT, (size_t)NV * NCLS, NV, b0);
    k_gemmPY<2><<<dim3(1, NV / 128, nb), blk, 0, stream>>>(
        P, (size_t)NV * NV, NV, YT, (size_t)NV * NCLS,
        NV, NV, NCLS, b3, out, b0);
  }
}

// Round 12
// 646.066 us; speedup vs baseline: 1.0558x; 1.0558x over previous
//
#include <hip/hip_runtime.h>
#include <hip/hip_bf16.h>
#include <stdint.h>

#define DEVI __device__ __forceinline__

typedef __bf16 bf16x8_t __attribute__((ext_vector_type(8)));
typedef float f32x4_t __attribute__((ext_vector_type(4)));
typedef unsigned short u16;

static constexpr int NBATCH = 16;
static constexpr int NV = 1024;
static constexpr int NE = 2048;
static constexpr int FV = 128;
static constexpr int FE = 64;
static constexpr int HID = 128;
static constexpr int NCLS = 16;

DEVI u16 f2bf(float f) { __hip_bfloat16 h = __float2bfloat16(f); return *reinterpret_cast<u16*>(&h); }
DEVI float bf2f(u16 u) { union { unsigned int i; float f; } x; x.i = ((unsigned int)u) << 16; return x.f; }

DEVI void gload_lds16(const void* g, void* l) {
  __builtin_amdgcn_global_load_lds(
      (const __attribute__((address_space(1))) unsigned int*)g,
      (__attribute__((address_space(3))) unsigned int*)l, 16, 0, 0);
}

// ---- K0: T (f32) -> T_bf + Tt_bf; optionally fused Asc1 = T * d1[col] ----
// Vectorized: 64x64 tile/block, float4 loads, uint2 stores (G13).
template <bool WRITE_ASC>
__global__ void k_transpose(const float* __restrict__ T, u16* __restrict__ Tbf,
                            u16* __restrict__ Ttbf, const float* __restrict__ d1,
                            u16* __restrict__ Asc1) {
  __shared__ u16 s[64][66];
  const int b = blockIdx.z;
  const int e0 = blockIdx.x * 64, v0 = blockIdx.y * 64;
  const float* Tb = T + (size_t)b * NV * NE;
  u16* T1 = Tbf + (size_t)b * NV * NE;
  u16* T2 = Ttbf + (size_t)b * NE * NV;
  const int c = threadIdx.x & 15, r = threadIdx.x >> 4;
  float4 dv = {0.f, 0.f, 0.f, 0.f};
  if (WRITE_ASC) dv = *(const float4*)(d1 + (size_t)b * NE + e0 + c * 4);
  #pragma unroll
  for (int i = 0; i < 4; ++i) {
    const int v = v0 + r + i * 16;
    float4 f = *(const float4*)(Tb + (size_t)v * NE + e0 + c * 4);
    u16 u0 = f2bf(f.x), u1 = f2bf(f.y), u2 = f2bf(f.z), u3 = f2bf(f.w);
    uint2 o;
    o.x = (unsigned)u0 | ((unsigned)u1 << 16);
    o.y = (unsigned)u2 | ((unsigned)u3 << 16);
    *(uint2*)(T1 + (size_t)v * NE + e0 + c * 4) = o;
    if (WRITE_ASC) {
      uint2 oa;
      oa.x = (unsigned)f2bf(f.x * dv.x) | ((unsigned)f2bf(f.y * dv.y) << 16);
      oa.y = (unsigned)f2bf(f.z * dv.z) | ((unsigned)f2bf(f.w * dv.w) << 16);
      *(uint2*)(Asc1 + (size_t)b * NV * NE + (size_t)v * NE + e0 + c * 4) = oa;
    }
    s[r + i * 16][c * 4 + 0] = u0;
    s[r + i * 16][c * 4 + 1] = u1;
    s[r + i * 16][c * 4 + 2] = u2;
    s[r + i * 16][c * 4 + 3] = u3;
  }
  __syncthreads();
  #pragma unroll
  for (int i = 0; i < 4; ++i) {
    const int e = r + i * 16;
    uint2 o;
    o.x = (unsigned)s[c * 4 + 0][e] | ((unsigned)s[c * 4 + 1][e] << 16);
    o.y = (unsigned)s[c * 4 + 2][e] | ((unsigned)s[c * 4 + 3][e] << 16);
    *(uint2*)(T2 + (size_t)(e0 + e) * NV + v0 + c * 4) = o;
  }
}

// ---- K1: d[b,r] = sum_c In[b,r,c] * p[c] ---- (one wave per row)
__global__ void k_rowdot(const float* __restrict__ In, const float* __restrict__ p,
                         float* __restrict__ d, int R, int C) {
  const int b = blockIdx.y;
  const int w = threadIdx.x >> 6, l = threadIdx.x & 63;
  const int r = blockIdx.x * 4 + w;
  const float* row = In + ((size_t)b * R + r) * C;
  float s = 0.f;
  for (int c = l; c < C; c += 64) s += row[c] * p[c];
  #pragma unroll
  for (int o = 32; o; o >>= 1) s += __shfl_xor(s, o);
  if (l == 0) d[(size_t)b * R + r] = s;
}

// ---- K2: Asc[bi, r, k] = In[bg, r, k] * d[bg, k]  (bf16 in/out) ----
__global__ void k_scale(const u16* __restrict__ In, const float* __restrict__ d,
                        u16* __restrict__ Out, int K, int b0) {
  const int bi = blockIdx.y, bg = b0 + bi;
  const size_t elems = (size_t)NV * NE;
  const size_t idx = ((size_t)blockIdx.x * 256 + threadIdx.x) * 8;
  const float* dd = d + (size_t)bg * K;
  const int k = (int)(idx & (size_t)(K - 1));
  const u16* in = In + (size_t)bg * elems + idx;
  uint4 raw = *(const uint4*)in;
  float f[8];
  f[0] = bf2f(raw.x & 0xffff); f[1] = bf2f(raw.x >> 16);
  f[2] = bf2f(raw.y & 0xffff); f[3] = bf2f(raw.y >> 16);
  f[4] = bf2f(raw.z & 0xffff); f[5] = bf2f(raw.z >> 16);
  f[6] = bf2f(raw.w & 0xffff); f[7] = bf2f(raw.w >> 16);
  u16 o[8];
  #pragma unroll
  for (int t = 0; t < 8; ++t) o[t] = f2bf(f[t] * dd[k + t]);
  *(uint4*)((u16*)Out + (size_t)bi * elems + idx) = *(uint4*)o;
}

// ---- K3: 256x256-tile GEMM  P[bi] = (diag?1:A*B^T) * adj[bg]  (round-6 best) ----
// stage(next) early, 1 barrier per K-tile, T2 XOR swizzle via inverse-swizzled
// source, XCD swizzle, setprio on MFMA. Epilogue: diag=1, *adj, bf16 P store,
// per-block column maxima pmax[bi][by][col] (no atomics).
__global__ __launch_bounds__(512, 2) void k_gemm256(
    const u16* __restrict__ A, size_t sA, int ldA,
    const u16* __restrict__ Bm, size_t sB, int ldB,
    int M, int K,
    const float* __restrict__ adj, u16* __restrict__ Pout,
    float* __restrict__ pmax, int b0) {
  extern __shared__ __align__(16) char smem[];
  const int gx = gridDim.x, gy = gridDim.y;
  const int total = gx * gy * gridDim.z;
  int orig = blockIdx.x + gx * (blockIdx.y + gy * blockIdx.z);
  const int cpx = total >> 3;
  int swz = (orig & 7) * cpx + (orig >> 3);
  const int bx = swz % gx;
  const int by = (swz / gx) % gy;
  const int bi = swz / (gx * gy);
  const int bg = b0 + bi;

  const u16* Ab = A + (size_t)bi * sA;
  const u16* Bb = Bm + (size_t)bg * sB;
  const int tm = by * 256, tn = bx * 256;
  const int tid = threadIdx.x, wid = tid >> 6, l = tid & 63;
  const int wr = wid >> 2, wc = wid & 3;

  const int srow = tid >> 3;
  const int scol = (((tid & 7) ^ (srow & 7)) << 3);

  const int Lx = (l & 7) << 4;
  const int colb0 = (((l >> 4) << 4)) ^ Lx;
  const int colb1 = (64 + ((l >> 4) << 4)) ^ Lx;
  const int arowb = (wr * 128 + (l & 15)) * 128;
  const int browb = (wc * 64 + (l & 15)) * 128;

  auto stage = [&](int buf, int k0) {
    char* ab = smem + (buf << 16);
    char* bb = ab + 32768;
    #pragma unroll
    for (int i = 0; i < 4; ++i) {
      gload_lds16(Ab + (size_t)(tm + i * 64 + srow) * ldA + (k0 + scol),
                  ab + i * 8192 + tid * 16);
      gload_lds16(Bb + (size_t)(tn + i * 64 + srow) * ldB + (k0 + scol),
                  bb + i * 8192 + tid * 16);
    }
  };

  f32x4_t acc[8][4];
  const f32x4_t zv = {0.f, 0.f, 0.f, 0.f};
  #pragma unroll
  for (int m = 0; m < 8; ++m)
    #pragma unroll
    for (int n = 0; n < 4; ++n) acc[m][n] = zv;

  const int NT = K >> 6;
  stage(0, 0);
  __syncthreads();

  for (int kt = 0; kt < NT; ++kt) {
    const int buf = kt & 1;
    if (kt + 1 < NT) stage(buf ^ 1, (kt + 1) << 6);
    char* abase = smem + (buf << 16);
    char* bbase = abase + 32768;
    bf16x8_t af[4][2], bfr[4][2];
    #pragma unroll
    for (int m = 0; m < 4; ++m) {
      af[m][0] = *(const bf16x8_t*)(abase + arowb + m * 2048 + colb0);
      af[m][1] = *(const bf16x8_t*)(abase + arowb + m * 2048 + colb1);
    }
    #pragma unroll
    for (int n = 0; n < 2; ++n) {
      bfr[n][0] = *(const bf16x8_t*)(bbase + browb + n * 2048 + colb0);
      bfr[n][1] = *(const bf16x8_t*)(bbase + browb + n * 2048 + colb1);
    }
    __builtin_amdgcn_s_setprio(1);
    #pragma unroll
    for (int m = 0; m < 4; ++m)
      #pragma unroll
      for (int n = 0; n < 2; ++n)
        #pragma unroll
        for (int kk = 0; kk < 2; ++kk)
          acc[m][n] = __builtin_amdgcn_mfma_f32_16x16x32_bf16(af[m][kk], bfr[n][kk], acc[m][n], 0, 0, 0);
    __builtin_amdgcn_s_setprio(0);
    #pragma unroll
    for (int n = 2; n < 4; ++n) {
      bfr[n][0] = *(const bf16x8_t*)(bbase + browb + n * 2048 + colb0);
      bfr[n][1] = *(const bf16x8_t*)(bbase + browb + n * 2048 + colb1);
    }
    __builtin_amdgcn_s_setprio(1);
    #pragma unroll
    for (int m = 0; m < 4; ++m)
      #pragma unroll
      for (int n = 2; n < 4; ++n)
        #pragma unroll
        for (int kk = 0; kk < 2; ++kk)
          acc[m][n] = __builtin_amdgcn_mfma_f32_16x16x32_bf16(af[m][kk], bfr[n][kk], acc[m][n], 0, 0, 0);
    __builtin_amdgcn_s_setprio(0);
    #pragma unroll
    for (int m = 0; m < 4; ++m) {
      af[m][0] = *(const bf16x8_t*)(abase + arowb + (m + 4) * 2048 + colb0);
      af[m][1] = *(const bf16x8_t*)(abase + arowb + (m + 4) * 2048 + colb1);
    }
    __builtin_amdgcn_s_setprio(1);
    #pragma unroll
    for (int m = 0; m < 4; ++m)
      #pragma unroll
      for (int n = 2; n < 4; ++n)
        #pragma unroll
        for (int kk = 0; kk < 2; ++kk)
          acc[m + 4][n] = __builtin_amdgcn_mfma_f32_16x16x32_bf16(af[m][kk], bfr[n][kk], acc[m + 4][n], 0, 0, 0);
    __builtin_amdgcn_s_setprio(0);
    __builtin_amdgcn_s_setprio(1);
    #pragma unroll
    for (int m = 0; m < 4; ++m)
      #pragma unroll
      for (int n = 0; n < 2; ++n)
        #pragma unroll
        for (int kk = 0; kk < 2; ++kk)
          acc[m + 4][n] = __builtin_amdgcn_mfma_f32_16x16x32_bf16(af[m][kk], bfr[n][kk], acc[m + 4][n], 0, 0, 0);
    __builtin_amdgcn_s_setprio(0);
    __syncthreads();
  }

  const float* adjb = adj + (size_t)bg * M * M;
  u16* Pb = Pout + (size_t)bi * (size_t)M * M;
  float vmax[4] = {0.f, 0.f, 0.f, 0.f};
  #pragma unroll
  for (int m = 0; m < 8; ++m)
    #pragma unroll
    for (int n = 0; n < 4; ++n)
      #pragma unroll
      for (int q = 0; q < 4; ++q) {
        int row = tm + wr * 128 + m * 16 + (l >> 4) * 4 + q;
        int col = tn + wc * 64 + n * 16 + (l & 15);
        float v = acc[m][n][q];
        if (row == col) v = 1.0f;
        v *= adjb[(size_t)row * M + col];
        vmax[n] = fmaxf(vmax[n], v);
        Pb[(size_t)row * M + col] = f2bf(v);
      }
  #pragma unroll
  for (int n = 0; n < 4; ++n) {
    vmax[n] = fmaxf(vmax[n], __shfl_xor(vmax[n], 16));
    vmax[n] = fmaxf(vmax[n], __shfl_xor(vmax[n], 32));
  }
  float* red = (float*)smem;
  if (l < 16) {
    #pragma unroll
    for (int n = 0; n < 4; ++n)
      red[((wr * 4 + wc) * 4 + n) * 16 + l] = vmax[n];
  }
  __syncthreads();
  if (wr == 0 && l < 16) {
    #pragma unroll
    for (int n = 0; n < 4; ++n) {
      float a = red[((0 * 4 + wc) * 4 + n) * 16 + l];
      float b = red[((1 * 4 + wc) * 4 + n) * 16 + l];
      pmax[((size_t)bi * gy + by) * M + tn + wc * 64 + n * 16 + l] = fmaxf(a, b);
    }
  }
}

// ---- K7: skinny 128x64-tile GEMM for P@Yc (col-sliced grid.x) ----
template <int EPI>
__global__ __launch_bounds__(256) void k_gemmPY(
    const u16* __restrict__ A, size_t sA, int ldA,
    const u16* __restrict__ Bm, size_t sB,
    int M, int K, int Ncols,
    const float* __restrict__ bias, float* __restrict__ Fout, int b0) {
  __shared__ __align__(16) u16 As[2][128 * 32];
  __shared__ __align__(16) u16 Bs[2][64 * 32];
  const int bi = blockIdx.z, bg = b0 + bi;
  const u16* Ab = A + (size_t)bi * sA;
  const u16* Bb = Bm + (size_t)bg * sB;
  const int tm = blockIdx.y * 128;
  const int cbase = blockIdx.x * 64;
  const int tid = threadIdx.x, w = tid >> 6, l = tid & 63;
  const int wm = (w >> 1) * 64, wn = (w & 1) * 32;
  const int lr = l & 15, kg = (l >> 4) * 8;
  const int chunk = l & 3;
  int arow[2];
  #pragma unroll
  for (int i = 0; i < 2; ++i) arow[i] = tm + (i * 4 + w) * 16 + (l >> 2);
  int brow = cbase + w * 16 + (l >> 2);
  if (brow >= Ncols) brow = Ncols - 1;

  f32x4_t acc[4][2];
  const f32x4_t zv = {0.f, 0.f, 0.f, 0.f};
  #pragma unroll
  for (int m = 0; m < 4; ++m)
    #pragma unroll
    for (int n = 0; n < 2; ++n) acc[m][n] = zv;

  auto stage = [&](int buf, int k0) {
    #pragma unroll
    for (int i = 0; i < 2; ++i)
      gload_lds16(Ab + (size_t)arow[i] * ldA + k0 + chunk * 8,
                  (char*)As[buf] + (i * 4 + w) * 1024);
    gload_lds16(Bb + (size_t)brow * ldA + k0 + chunk * 8,
                (char*)Bs[buf] + tid * 16);
  };

  const int nsteps = K >> 5;
  stage(0, 0);
  __syncthreads();
  for (int s = 0; s < nsteps; ++s) {
    const int cur = s & 1;
    if (s + 1 < nsteps) stage(cur ^ 1, (s + 1) << 5);
    bf16x8_t af[4], bfr[2];
    #pragma unroll
    for (int m = 0; m < 4; ++m) af[m] = *(const bf16x8_t*)&As[cur][(wm + m * 16 + lr) * 32 + kg];
    #pragma unroll
    for (int n = 0; n < 2; ++n) bfr[n] = *(const bf16x8_t*)&Bs[cur][(wn + n * 16 + lr) * 32 + kg];
    #pragma unroll
    for (int m = 0; m < 4; ++m)
      #pragma unroll
      for (int n = 0; n < 2; ++n)
        acc[m][n] = __builtin_amdgcn_mfma_f32_16x16x32_bf16(af[m], bfr[n], acc[m][n], 0, 0, 0);
    __syncthreads();
  }

  float* Ob = Fout + (size_t)bg * M * Ncols;
  #pragma unroll
  for (int m = 0; m < 4; ++m)
    #pragma unroll
    for (int n = 0; n < 2; ++n)
      #pragma unroll
      for (int q = 0; q < 4; ++q) {
        int row = tm + wm + m * 16 + (l >> 4) * 4 + q;
        int col = cbase + wn + n * 16 + lr;
        if (col < Ncols) {
          float v = acc[m][n][q] + bias[col];
          if (EPI == 1) v = fmaxf(v, 0.f);
          Ob[(size_t)row * Ncols + col] = v;
        }
      }
}

// ---- K5: YT[bg, c, j] = bf16( (X@W)[j,c] / colmax_j ), colmax fused from pmax ----
template <bool RELU_IN>
__global__ __launch_bounds__(256) void k_smallgemm(
    const float* __restrict__ X, size_t sX, int Kd,
    const float* __restrict__ W, int Cc,
    const float* __restrict__ pmax, int G, u16* __restrict__ YT, size_t sY,
    int Nj, int b0) {
  __shared__ float Xs[64][129];
  __shared__ float Ws[128][33];
  const int bi = blockIdx.y, bg = b0 + bi;
  const float* Xb = X + (size_t)bg * sX;
  const int j0 = blockIdx.x * 64;
  const int tid = threadIdx.x;
  for (int idx = tid; idx < 64 * (Kd / 4); idx += 256) {
    int r = idx / (Kd / 4), q = idx % (Kd / 4);
    float4 v = *(const float4*)(Xb + (size_t)(j0 + r) * Kd + q * 4);
    if (RELU_IN) {
      v.x = fmaxf(v.x, 0.f); v.y = fmaxf(v.y, 0.f);
      v.z = fmaxf(v.z, 0.f); v.w = fmaxf(v.w, 0.f);
    }
    Xs[r][q * 4 + 0] = v.x; Xs[r][q * 4 + 1] = v.y;
    Xs[r][q * 4 + 2] = v.z; Xs[r][q * 4 + 3] = v.w;
  }
  const int r = tid & 63, cg = tid >> 6;
  float mx = 0.f;
  {
    const float* pb = pmax + (size_t)bi * G * Nj + (j0 + r);
    for (int g = 0; g < G; ++g) mx = fmaxf(mx, pb[(size_t)g * Nj]);
  }
  const float rinv = 1.0f / mx;
  for (int c0 = 0; c0 < Cc; c0 += 32) {
    __syncthreads();
    for (int idx = tid; idx < Kd * 32; idx += 256) {
      int k = idx >> 5, c = c0 + (idx & 31);
      Ws[k][idx & 31] = (c < Cc) ? W[(size_t)k * Cc + c] : 0.f;
    }
    __syncthreads();
    float acc[8] = {0.f, 0.f, 0.f, 0.f, 0.f, 0.f, 0.f, 0.f};
    for (int k = 0; k < Kd; ++k) {
      float xv = Xs[r][k];
      #pragma unroll
      for (int cc = 0; cc < 8; ++cc) acc[cc] += xv * Ws[k][cg * 8 + cc];
    }
    #pragma unroll
    for (int cc = 0; cc < 8; ++cc) {
      int c = c0 + cg * 8 + cc;
      if (c < Cc) YT[(size_t)bg * sY + (size_t)c * Nj + j0 + r] = f2bf(acc[cc] * rinv);
    }
  }
}

extern "C" void kernel_launch(void* const* d_in, const int* in_sizes, int n_in,
                              void* d_out, int out_size, void* d_ws, size_t ws_size,
                              hipStream_t stream) {
  const float* X    = (const float*)d_in[0];
  const float* Z    = (const float*)d_in[1];
  const float* adje = (const float*)d_in[2];
  const float* adjv = (const float*)d_in[3];
  const float* T    = (const float*)d_in[4];
  const float* W1   = (const float*)d_in[5];
  const float* b1   = (const float*)d_in[6];
  const float* p1   = (const float*)d_in[7];
  const float* W2   = (const float*)d_in[8];
  const float* b2   = (const float*)d_in[9];
  const float* p2   = (const float*)d_in[10];
  const float* W3   = (const float*)d_in[11];
  const float* b3   = (const float*)d_in[12];
  const float* p3   = (const float*)d_in[13];
  float* out = (float*)d_out;
  (void)in_sizes; (void)n_in; (void)out_size;

  hipFuncSetAttribute(reinterpret_cast<const void*>(k_gemm256),
                      hipFuncAttributeMaxDynamicSharedMemorySize, 131072);

  char* ws = (char*)d_ws;
  size_t off = 0;
  auto alloc = [&](size_t n) -> char* {
    char* p = ws + off; off = (off + n + 255) & ~(size_t)255; return p;
  };
  u16* Tbf    = (u16*)alloc((size_t)NBATCH * NV * NE * 2);
  u16* Ttbf   = (u16*)alloc((size_t)NBATCH * NE * NV * 2);
  float* dbuf = (float*)alloc((size_t)NBATCH * NE * 4);
  float* pmax = (float*)alloc((size_t)NBATCH * 16 * NE * 4);
  u16* YT     = (u16*)alloc((size_t)NBATCH * NE * 64 * 2);
  float* x1   = (float*)alloc((size_t)NBATCH * NV * HID * 4);
  float* z2   = (float*)alloc((size_t)NBATCH * NE * FE * 4);
  const size_t needA = (size_t)NBATCH * NV * NE * 2;
  const size_t needP = (size_t)NBATCH * NE * NE * 2;
  const bool full = (ws_size >= off + needA + needP + 1024);
  const int nb = full ? NBATCH : 1;
  u16* Asc = (u16*)alloc(full ? needA : (size_t)NV * NE * 2);
  u16* P   = (u16*)alloc(full ? needP : (size_t)NE * NE * 2);

  const dim3 blk(256, 1, 1);
  const dim3 blk512(512, 1, 1);

  // d1 must exist before the (fused) transpose
  k_rowdot<<<dim3(NE / 4, NBATCH), blk, 0, stream>>>(Z, p1, dbuf, NE, FE);
  if (full)
    k_transpose<true><<<dim3(NE / 64, NV / 64, NBATCH), blk, 0, stream>>>(
        T, Tbf, Ttbf, dbuf, Asc);
  else
    k_transpose<false><<<dim3(NE / 64, NV / 64, NBATCH), blk, 0, stream>>>(
        T, Tbf, Ttbf, nullptr, nullptr);

  // ---------------- Layer 1 (node: Fv -> H) ----------------
  for (int b0 = 0; b0 < NBATCH; b0 += nb) {
    if (!full)
      k_scale<<<dim3((NV * NE) / 2048, nb), blk, 0, stream>>>(Tbf, dbuf, Asc, NE, b0);
    k_gemm256<<<dim3(NV / 256, NV / 256, nb), blk512, 131072, stream>>>(
        Asc, (size_t)NV * NE, NE, Tbf, (size_t)NV * NE, NE, NV, NE, adjv, P, pmax, b0);
    k_smallgemm<false><<<dim3(NV / 64, nb), blk, 0, stream>>>(
        X, (size_t)NV * FV, FV, W1, HID, pmax, NV / 256, YT, (size_t)NV * HID, NV, b0);
    k_gemmPY<1><<<dim3(2, NV / 128, nb), blk, 0, stream>>>(
        P, (size_t)NV * NV, NV, YT, (size_t)NV * HID,
        NV, NV, HID, b1, x1, b0);
  }
  // ---------------- Layer 2 (edge: Fe -> Fe) ----------------
  k_rowdot<<<dim3(NV / 4, NBATCH), blk, 0, stream>>>(x1, p2, dbuf, NV, HID);
  for (int b0 = 0; b0 < NBATCH; b0 += nb) {
    k_scale<<<dim3((NE * NV) / 2048, nb), blk, 0, stream>>>(Ttbf, dbuf, Asc, NV, b0);
    k_gemm256<<<dim3(NE / 256, NE / 256, nb), blk512, 131072, stream>>>(
        Asc, (size_t)NE * NV, NV, Ttbf, (size_t)NE * NV, NV, NE, NV, adje, P, pmax, b0);
    k_smallgemm<true><<<dim3(NE / 64, nb), blk, 0, stream>>>(
        Z, (size_t)NE * FE, FE, W2, FE, pmax, NE / 256, YT, (size_t)NE * FE, NE, b0);
    k_gemmPY<1><<<dim3(1, NE / 128, nb), blk, 0, stream>>>(
        P, (size_t)NE * NE, NE, YT, (size_t)NE * FE,
        NE, NE, FE, b2, z2, b0);
  }
  // ---------------- Layer 3 (node: H -> C) ----------------
  k_rowdot<<<dim3(NE / 4, NBATCH), blk, 0, stream>>>(z2, p3, dbuf, NE, FE);
  for (int b0 = 0; b0 < NBATCH; b0 += nb) {
    k_scale<<<dim3((NV * NE) / 2048, nb), blk, 0, stream>>>(Tbf, dbuf, Asc, NE, b0);
    k_gemm256<<<dim3(NV / 256, NV / 256, nb), blk512, 131072, stream>>>(
        Asc, (size_t)NV * NE, NE, Tbf, (size_t)NV * NE, NE, NV, NE, adjv, P, pmax, b0);
    k_smallgemm<false><<<dim3(NV / 64, nb), blk, 0, stream>>>(
        x1, (size_t)NV * HID, HID, W3, NCLS, pmax, NV / 256, YT, (size_t)NV * NCLS, NV, b0);
    k_gemmPY<2><<<dim3(1, NV / 128, nb), blk, 0, stream>>>(
        P, (size_t)NV * NV, NV, YT, (size_t)NV * NCLS,
        NV, NV, NCLS, b3, out, b0);
  }
}